// Round 13
// baseline (177.650 us; speedup 1.0000x reference)
//
#include <hip/hip_runtime.h>
#include <stdint.h>
#include <float.h>

#define TOTAL 16368
#define KSEL 500
#define HQ 704            // per-half g0 cap (4096 @ thr1.10: mean 556, +6.6sd)
#define NSH 22            // 2*HQ/64
#define NBUCKET 64

// order-preserving float<->uint key (monotonic increasing on finite floats)
__device__ __forceinline__ uint32_t fkey(float f) {
    uint32_t u = __float_as_uint(f);
    return (u & 0x80000000u) ? ~u : (u | 0x80000000u);
}
__device__ __forceinline__ float keyf(uint32_t k) {
    uint32_t u = (k & 0x80000000u) ? (k & 0x7FFFFFFFu) : ~k;
    return __uint_as_float(u);
}
__device__ __forceinline__ int lanerank(uint64_t m) {
    return __builtin_amdgcn_mbcnt_hi((uint32_t)(m >> 32),
           __builtin_amdgcn_mbcnt_lo((uint32_t)m, 0));
}
__device__ __forceinline__ int wave_sumi(int v) {
    #pragma unroll
    for (int o = 32; o > 0; o >>= 1) v += __shfl_xor(v, o, 64);
    return v;
}
__device__ __forceinline__ float wave_sumf(float v) {
    #pragma unroll
    for (int o = 32; o > 0; o >>= 1) v += __shfl_xor(v, o, 64);
    return v;
}
__device__ __forceinline__ float wave_maxf(float v) {
    #pragma unroll
    for (int o = 32; o > 0; o >>= 1) v = fmaxf(v, __shfl_xor(v, o, 64));
    return v;
}
__device__ __forceinline__ void lse_merge(float& m, float& l, float m2, float l2) {
    float M = fmaxf(m, m2);
    l = l * __expf(m - M) + l2 * __expf(m2 - M);
    m = M;
}

// exact exhaustive fallback (never taken for N(0,1) bench data); returns kl on
// lane 0 (0 elsewhere). Bisection on 45-bit key (fkey<<13 | (8191-idx)).
__device__ __noinline__ float wave_slow_kl(const float* __restrict__ t,
                                           const float* __restrict__ s, int C) {
    const int lane = threadIdx.x & 63;
    uint64_t lo = 0ull, hi = (1ull << 45), tau = 0ull;
    int cl = C, ch = 0;
    #pragma unroll 1
    for (int it = 0; it < 100; ++it) {
        uint64_t span = hi - lo;
        if (span <= 1ull) { tau = lo; break; }
        uint64_t mid;
        if (it & 1) mid = lo + (span >> 1);
        else {
            uint64_t st = span * (uint64_t)(cl - KSEL) / (uint64_t)(cl - ch);
            if (st < 1) st = 1;
            if (st > span - 1) st = span - 1;
            mid = lo + st;
        }
        int c = 0;
        #pragma unroll 1
        for (int i = lane; i < C; i += 64) {
            uint64_t ck = ((uint64_t)fkey(t[i]) << 13) | (uint64_t)(8191 - i);
            c += (ck > mid);
        }
        c = wave_sumi(c);
        if (c == KSEL) { tau = mid; break; }
        if (c > KSEL) { lo = mid; cl = c; } else { hi = mid; ch = c; }
    }
    float tmx = -FLT_MAX;
    for (int i = lane; i < C; i += 64) tmx = fmaxf(tmx, t[i]);
    tmx = wave_maxf(tmx);
    float St = 0.f, Stt = 0.f, Sts = 0.f, sm = -FLT_MAX;
    #pragma unroll 1
    for (int i = lane; i < C; i += 64) {
        float x = t[i];
        uint64_t ck = ((uint64_t)fkey(x) << 13) | (uint64_t)(8191 - i);
        if (ck > tau) {
            float e = __expf(x - tmx), v = s[i];
            St += e; Stt += e * x; Sts += e * v;
            sm = fmaxf(sm, v);
        }
    }
    St = wave_sumf(St); Stt = wave_sumf(Stt); Sts = wave_sumf(Sts); sm = wave_maxf(sm);
    float Ss = 0.f;
    #pragma unroll 1
    for (int i = lane; i < C; i += 64) {
        uint64_t ck = ((uint64_t)fkey(t[i]) << 13) | (uint64_t)(8191 - i);
        if (ck > tau) Ss += __expf(s[i] - sm);
    }
    Ss = wave_sumf(Ss);
    if (lane == 0)
        return (Stt - Sts) / St - tmx - __logf(St) + sm + __logf(Ss);
    return 0.f;
}

// Big group in ONE wave (C = NF4*256), proven R10 late-gather path: teacher
// double-buffered stream; ballot compaction of (val,idx) to LDS; bisection on
// register keys; student gathered ONLY for selected slots. kl on lane 0.
template <int NF4, int CAPT, int NST>
__device__ float big_wave(const float* __restrict__ tg, const float* __restrict__ s,
                          float thr, float* vals, uint16_t* idxs) {
    const int lane = threadIdx.x & 63;
    const float4* t4 = (const float4*)tg;
    constexpr int NB = NF4 / 8;
    int cnt = 0;
    float4 buf[8], nxt[8];
    #pragma unroll
    for (int u = 0; u < 8; ++u) buf[u] = t4[u * 64 + lane];
    #pragma unroll 1
    for (int b = 0; b < NB; ++b) {
        if (b + 1 < NB) {
            #pragma unroll
            for (int u = 0; u < 8; ++u)
                nxt[u] = t4[((b + 1) * 8 + u) * 64 + lane];
        }
        #pragma unroll
        for (int u = 0; u < 8; ++u) {
            float xs[4] = {buf[u].x, buf[u].y, buf[u].z, buf[u].w};
            #pragma unroll
            for (int q = 0; q < 4; ++q) {
                bool p = xs[q] > thr;
                uint64_t m = __ballot(p);
                if (p) {
                    int ofs = cnt + lanerank(m);
                    if (ofs < CAPT) {
                        vals[ofs] = xs[q];
                        idxs[ofs] = (uint16_t)((((b * 8 + u) * 64 + lane) << 2) + q);
                    }
                }
                cnt += (int)__popcll(m);
            }
        }
        if (b + 1 < NB) {
            #pragma unroll
            for (int u = 0; u < 8; ++u) buf[u] = nxt[u];
        }
    }
    if (cnt < KSEL || cnt > CAPT) return wave_slow_kl(tg, s, NF4 * 256);

    uint32_t key[NST];
    #pragma unroll
    for (int j = 0; j < NST; ++j) {
        int p = lane + j * 64;
        key[j] = (p < cnt) ? fkey(vals[p]) : 0u;
    }
    uint32_t kmx = 0u, kmn = 0xFFFFFFFFu;
    #pragma unroll
    for (int j = 0; j < NST; ++j) {
        uint32_t k = key[j];
        kmx = k > kmx ? k : kmx;
        if (k) kmn = k < kmn ? k : kmn;
    }
    #pragma unroll
    for (int o = 32; o > 0; o >>= 1) {
        uint32_t a = __shfl_xor(kmx, o, 64); kmx = a > kmx ? a : kmx;
        uint32_t b2 = __shfl_xor(kmn, o, 64); kmn = b2 < kmn ? b2 : kmn;
    }
    const float tmax = keyf(kmx);

    uint32_t lo = kmn - 1u, hi = kmx, tauhi = kmx;
    int cl = cnt, ch = 0, cut = -1;
    bool exact = false;
    #pragma unroll 1
    for (int it = 0; it < 80; ++it) {
        uint32_t span = hi - lo;
        if (span <= 1u) break;
        uint32_t mid;
        if (!(it & 1)) {  // false position on empirical CDF
            uint64_t st = (uint64_t)span * (uint32_t)(cl - KSEL) / (uint32_t)(cl - ch);
            if (st < 1) st = 1;
            if (st > span - 1) st = span - 1;
            mid = lo + (uint32_t)st;
        } else mid = lo + (span >> 1);
        int c = 0;
        #pragma unroll
        for (int j = 0; j < NST; ++j)
            c += (int)__popcll(__ballot(key[j] > mid));
        if (c == KSEL) { tauhi = mid; exact = true; break; }
        if (c > KSEL) { lo = mid; cl = c; } else { hi = mid; ch = c; }
    }
    if (!exact) {
        tauhi = hi;
        const int nT = KSEL - ch, nTie = cl - ch;
        if (nT >= nTie) cut = 0x7FFFFFFF;
        else {
            int idxr[NST];
            #pragma unroll
            for (int j = 0; j < NST; ++j) {
                int p = lane + j * 64;
                idxr[j] = (p < cnt) ? (int)idxs[p] : 0x7FFF;
            }
            int l = -1, h = 8191;
            #pragma unroll 1
            while (h - l > 1) {
                int m = (l + h) >> 1;
                int c = 0;
                #pragma unroll
                for (int j = 0; j < NST; ++j)
                    c += (int)__popcll(__ballot(key[j] == tauhi && idxr[j] <= m));
                if (c >= nT) h = m; else l = m;
            }
            cut = h;
        }
    }

    uint32_t selm = 0u;
    if (cut == -1) {
        #pragma unroll
        for (int j = 0; j < NST; ++j) selm |= (key[j] > tauhi ? 1u : 0u) << j;
    } else if (cut == 0x7FFFFFFF) {
        #pragma unroll
        for (int j = 0; j < NST; ++j) selm |= (key[j] >= tauhi ? 1u : 0u) << j;
    } else {
        #pragma unroll
        for (int j = 0; j < NST; ++j) {
            int p = lane + j * 64;
            bool sj = (key[j] > tauhi) ||
                      (key[j] == tauhi && p < cnt && (int)idxs[p] <= cut);
            selm |= (sj ? 1u : 0u) << j;
        }
    }

    float svc[NST];
    #pragma unroll
    for (int j = 0; j < NST; ++j)
        svc[j] = (selm & (1u << j)) ? s[(int)idxs[lane + j * 64]] : 0.f;

    float St = 0.f, Stt = 0.f, Sts = 0.f, sm = -FLT_MAX;
    #pragma unroll
    for (int j = 0; j < NST; ++j) {
        if (selm & (1u << j)) {
            float tv = keyf(key[j]);
            float e = __expf(tv - tmax);
            St += e; Stt += e * tv; Sts += e * svc[j];
            sm = fmaxf(sm, svc[j]);
        }
    }
    #pragma unroll
    for (int o = 32; o > 0; o >>= 1) {
        St  += __shfl_xor(St,  o, 64);
        Stt += __shfl_xor(Stt, o, 64);
        Sts += __shfl_xor(Sts, o, 64);
        sm = fmaxf(sm, __shfl_xor(sm, o, 64));
    }
    float Ss = 0.f;
    #pragma unroll
    for (int j = 0; j < NST; ++j)
        if (selm & (1u << j)) Ss += __expf(svc[j] - sm);
    Ss = wave_sumf(Ss);
    if (lane == 0)
        return (Stt - Sts) / St - tmax - __logf(St) + sm + __logf(Ss);
    return 0.f;
}

// g0 half (4096 floats) in one wave: R10's compaction loop (NF4=16) writing
// (fkey, group-global idx) into this wave's PRIVATE HQ-slot LDS segment.
__device__ int half_compact(const float* __restrict__ tq, int idx_off,
                            uint32_t* kv, uint16_t* ix) {
    const int lane = threadIdx.x & 63;
    const float4* t4 = (const float4*)tq;
    int cnt = 0;
    float4 buf[8], nxt[8];
    #pragma unroll
    for (int u = 0; u < 8; ++u) buf[u] = t4[u * 64 + lane];
    #pragma unroll 1
    for (int b = 0; b < 2; ++b) {
        if (b == 0) {
            #pragma unroll
            for (int u = 0; u < 8; ++u) nxt[u] = t4[(8 + u) * 64 + lane];
        }
        #pragma unroll
        for (int u = 0; u < 8; ++u) {
            float xs[4] = {buf[u].x, buf[u].y, buf[u].z, buf[u].w};
            #pragma unroll
            for (int q = 0; q < 4; ++q) {
                bool p = xs[q] > 1.10f;
                uint64_t m = __ballot(p);
                if (p) {
                    int ofs = cnt + lanerank(m);
                    if (ofs < HQ) {
                        kv[ofs] = fkey(xs[q]);
                        ix[ofs] = (uint16_t)(((((b * 8 + u) * 64 + lane) << 2) + q)
                                             + idx_off);
                    }
                }
                cnt += (int)__popcll(m);
            }
        }
        if (b == 0) {
            #pragma unroll
            for (int u = 0; u < 8; ++u) buf[u] = nxt[u];
        }
    }
    if (cnt <= HQ)
        for (int p = cnt + lane; p < HQ; p += 64) kv[p] = 0u;  // pad unselectable
    return cnt;
}

// g0 select over the 2 LDS half-segments (keys to regs, ballot bisection,
// LATE student gather for selected slots only). Returns kl on lane 0.
__device__ float pair_select(const uint32_t* __restrict__ kv,
                             const uint16_t* __restrict__ ix,
                             const int* __restrict__ cnts,
                             const float* __restrict__ tg,
                             const float* __restrict__ sg) {
    const int lane = threadIdx.x & 63;
    const int tot = cnts[0] + cnts[1];
    if (cnts[0] > HQ || cnts[1] > HQ || tot < KSEL)
        return wave_slow_kl(tg, sg, 8192);

    uint32_t key[NSH];
    #pragma unroll
    for (int j = 0; j < NSH; ++j) key[j] = kv[lane + j * 64];

    uint32_t kmx = 0u, kmn = 0xFFFFFFFFu;
    #pragma unroll
    for (int j = 0; j < NSH; ++j) {
        uint32_t k = key[j];
        kmx = k > kmx ? k : kmx;
        if (k) kmn = k < kmn ? k : kmn;
    }
    #pragma unroll
    for (int o = 32; o > 0; o >>= 1) {
        uint32_t a = __shfl_xor(kmx, o, 64); kmx = a > kmx ? a : kmx;
        uint32_t b2 = __shfl_xor(kmn, o, 64); kmn = b2 < kmn ? b2 : kmn;
    }
    const float tmax = keyf(kmx);

    uint32_t lo = kmn - 1u, hi = kmx, tauhi = kmx;
    int cl = tot, ch = 0, cut = -1;
    bool exact = false;
    #pragma unroll 1
    for (int it = 0; it < 80; ++it) {
        uint32_t span = hi - lo;
        if (span <= 1u) break;
        uint32_t mid;
        if (!(it & 1)) {  // false position on empirical CDF
            uint64_t st = (uint64_t)span * (uint32_t)(cl - KSEL) / (uint32_t)(cl - ch);
            if (st < 1) st = 1;
            if (st > span - 1) st = span - 1;
            mid = lo + (uint32_t)st;
        } else mid = lo + (span >> 1);
        int c = 0;
        #pragma unroll
        for (int j = 0; j < NSH; ++j)
            c += (int)__popcll(__ballot(key[j] > mid));
        if (c == KSEL) { tauhi = mid; exact = true; break; }
        if (c > KSEL) { lo = mid; cl = c; } else { hi = mid; ch = c; }
    }
    if (!exact) {
        tauhi = hi;
        const int nT = KSEL - ch, nTie = cl - ch;
        if (nT >= nTie) cut = 0x7FFFFFFF;
        else {  // padded keys are 0 != tauhi, so garbage ix never counted
            int l = -1, h = 8191;
            #pragma unroll 1
            while (h - l > 1) {
                int m = (l + h) >> 1;
                int c = 0;
                #pragma unroll
                for (int j = 0; j < NSH; ++j)
                    c += (int)__popcll(__ballot(key[j] == tauhi &&
                                                (int)ix[lane + j * 64] <= m));
                if (c >= nT) h = m; else l = m;
            }
            cut = h;
        }
    }

    uint32_t selm = 0u;
    if (cut == -1) {
        #pragma unroll
        for (int j = 0; j < NSH; ++j) selm |= (key[j] > tauhi ? 1u : 0u) << j;
    } else if (cut == 0x7FFFFFFF) {
        #pragma unroll
        for (int j = 0; j < NSH; ++j) selm |= (key[j] >= tauhi ? 1u : 0u) << j;
    } else {
        #pragma unroll
        for (int j = 0; j < NSH; ++j) {
            bool sj = (key[j] > tauhi) ||
                      (key[j] == tauhi && (int)ix[lane + j * 64] <= cut);
            selm |= (sj ? 1u : 0u) << j;
        }
    }

    float svc[NSH];
    #pragma unroll
    for (int j = 0; j < NSH; ++j)
        svc[j] = (selm & (1u << j)) ? sg[(int)ix[lane + j * 64]] : 0.f;

    float St = 0.f, Stt = 0.f, Sts = 0.f, sm = -FLT_MAX;
    #pragma unroll
    for (int j = 0; j < NSH; ++j) {
        if (selm & (1u << j)) {
            float tv = keyf(key[j]);
            float e = __expf(tv - tmax);
            St += e; Stt += e * tv; Sts += e * svc[j];
            sm = fmaxf(sm, svc[j]);
        }
    }
    #pragma unroll
    for (int o = 32; o > 0; o >>= 1) {
        St  += __shfl_xor(St,  o, 64);
        Stt += __shfl_xor(Stt, o, 64);
        Sts += __shfl_xor(Sts, o, 64);
        sm = fmaxf(sm, __shfl_xor(sm, o, 64));
    }
    float Ss = 0.f;
    #pragma unroll
    for (int j = 0; j < NSH; ++j)
        if (selm & (1u << j)) Ss += __expf(svc[j] - sm);
    Ss = wave_sumf(Ss);
    if (lane == 0)
        return (Stt - Sts) / St - tmax - __logf(St) + sm + __logf(Ss);
    return 0.f;
}

// Exact top-KSEL + KL on dense register-resident keys, BALLOT bisection.
template <int NS, class IdxF>
__device__ float select_accum(uint32_t (&key)[NS], IdxF idxOf, const float* svp) {
    const int lane = threadIdx.x & 63;
    uint32_t kmx = 0u, kmn = 0xFFFFFFFFu;
    #pragma unroll
    for (int j = 0; j < NS; ++j) {
        uint32_t k = key[j];
        kmx = k > kmx ? k : kmx;
        kmn = k < kmn ? k : kmn;
    }
    #pragma unroll
    for (int o = 32; o > 0; o >>= 1) {
        uint32_t a = __shfl_xor(kmx, o, 64); kmx = a > kmx ? a : kmx;
        uint32_t b = __shfl_xor(kmn, o, 64); kmn = b < kmn ? b : kmn;
    }
    const float tmax = keyf(kmx);

    uint32_t lo = kmn - 1u, hi = kmx, tauhi = kmx;
    int cl = NS * 64, ch = 0, cut = -1;
    bool exact = false;
    #pragma unroll 1
    for (int it = 0; it < 80; ++it) {
        uint32_t span = hi - lo;
        if (span <= 1u) break;
        uint32_t mid;
        if (!(it & 1)) {
            uint64_t st = (uint64_t)span * (uint32_t)(cl - KSEL) / (uint32_t)(cl - ch);
            if (st < 1) st = 1;
            if (st > span - 1) st = span - 1;
            mid = lo + (uint32_t)st;
        } else mid = lo + (span >> 1);
        int c = 0;
        #pragma unroll
        for (int j = 0; j < NS; ++j)
            c += (int)__popcll(__ballot(key[j] > mid));
        if (c == KSEL) { tauhi = mid; exact = true; break; }
        if (c > KSEL) { lo = mid; cl = c; } else { hi = mid; ch = c; }
    }
    if (!exact) {
        tauhi = hi;
        const int nT = KSEL - ch, nTie = cl - ch;
        if (nT >= nTie) cut = 0x7FFFFFFF;
        else {
            int l = -1, h = NS * 64 - 1;
            #pragma unroll 1
            while (h - l > 1) {
                int m = (l + h) >> 1;
                int c = 0;
                #pragma unroll
                for (int j = 0; j < NS; ++j)
                    c += (int)__popcll(__ballot(key[j] == tauhi && idxOf(j) <= m));
                if (c >= nT) h = m; else l = m;
            }
            cut = h;
        }
    }

    float St = 0.f, Stt = 0.f, Sts = 0.f, sm = -FLT_MAX;
    #pragma unroll
    for (int j = 0; j < NS; ++j) {
        uint32_t kj = key[j];
        bool sj = (kj > tauhi) || (kj == tauhi && idxOf(j) <= cut);
        if (sj) {
            float tv = keyf(kj);
            float e = __expf(tv - tmax);
            St += e; Stt += e * tv; Sts += e * svp[j];
            sm = fmaxf(sm, svp[j]);
        }
    }
    #pragma unroll
    for (int o = 32; o > 0; o >>= 1) {
        St  += __shfl_xor(St,  o, 64);
        Stt += __shfl_xor(Stt, o, 64);
        Sts += __shfl_xor(Sts, o, 64);
        sm = fmaxf(sm, __shfl_xor(sm, o, 64));
    }
    float Ss = 0.f;
    #pragma unroll
    for (int j = 0; j < NS; ++j) {
        uint32_t kj = key[j];
        bool sj = (kj > tauhi) || (kj == tauhi && idxOf(j) <= cut);
        if (sj) Ss += __expf(svp[j] - sm);
    }
    Ss = wave_sumf(Ss);
    if (lane == 0)
        return (Stt - Sts) / St - tmax - __logf(St) + sm + __logf(Ss);
    return 0.f;
}

// mid groups (C = NJ*64): whole group + student prefetched to registers
template <int NJ>
__device__ float mid_wave(const float* __restrict__ t, const float* __restrict__ s) {
    const int lane = threadIdx.x & 63;
    const float4* t4 = (const float4*)t;
    const float4* s4 = (const float4*)s;
    uint32_t key[NJ];
    float svp[NJ];
    #pragma unroll
    for (int c = 0; c < NJ / 4; ++c) {
        float4 x = t4[lane + c * 64];
        float4 y = s4[lane + c * 64];
        key[4 * c + 0] = fkey(x.x); key[4 * c + 1] = fkey(x.y);
        key[4 * c + 2] = fkey(x.z); key[4 * c + 3] = fkey(x.w);
        svp[4 * c + 0] = y.x; svp[4 * c + 1] = y.y;
        svp[4 * c + 2] = y.z; svp[4 * c + 3] = y.w;
    }
    auto idxOf = [&](int j) { return ((lane + (j >> 2) * 64) << 2) + (j & 3); };
    return select_accum<NJ>(key, idxOf, svp);
}

// tiny groups (k == C <= 256): whole-group softmax; returns kl on lane 0
__device__ float tiny_group(const float* __restrict__ t, const float* __restrict__ s,
                            int Cg) {
    const int lane = threadIdx.x & 63;
    float St = 0.f, Stt = 0.f, Sts = 0.f, m = -FLT_MAX, l = 0.f;
    float tv[4], svv[4];
    #pragma unroll
    for (int q = 0; q < 4; ++q) {
        int i = lane + q * 64;
        bool va = i < Cg;
        tv[q] = va ? t[i] : -FLT_MAX;
        svv[q] = va ? s[i] : 0.f;
    }
    float mx = -FLT_MAX;
    #pragma unroll
    for (int q = 0; q < 4; ++q) mx = fmaxf(mx, tv[q]);
    mx = wave_maxf(mx);
    #pragma unroll
    for (int q = 0; q < 4; ++q) {
        if (lane + q * 64 < Cg) {
            float e = __expf(tv[q] - mx);
            St += e; Stt += e * tv[q]; Sts += e * svv[q];
            float x = svv[q];
            if (x > m) { l = l * __expf(m - x) + 1.f; m = x; }
            else       { l += __expf(x - m); }
        }
    }
    #pragma unroll
    for (int o = 32; o > 0; o >>= 1) {
        St  += __shfl_xor(St,  o, 64);
        Stt += __shfl_xor(Stt, o, 64);
        Sts += __shfl_xor(Sts, o, 64);
        float m2 = __shfl_xor(m, o, 64);
        float l2 = __shfl_xor(l, o, 64);
        lse_merge(m, l, m2, l2);
    }
    if (lane == 0)
        return (Stt - Sts) / St - mx - __logf(St) + m + __logf(l);
    return 0.f;
}

// 3072 blocks x 128 threads (2 waves):
//  A (bid<1024):       w0/w1 = g0 halves (32KB each, IDENTICAL work -> barrier
//                      convoy ~0); one __syncthreads; w0 selects (late-gather).
//  B (1024..2047):     w0 = g1 (big_wave late-gather), w1 = g2. NO barrier.
//  C (2048..3071):     w0 = g3, w1 = g4 + tinies.     NO barrier.
// Longest wave drops 64KB -> ~33KB; durations cluster -> occupancy holds.
__global__ __launch_bounds__(128, 6) void kd_mix(const float* __restrict__ sL,
                                                 const float* __restrict__ tL,
                                                 float* __restrict__ partial) {
    __shared__ char smem[12544] __attribute__((aligned(16)));
    __shared__ int cnts[2];
    const int bid = blockIdx.x;
    const int w = threadIdx.x >> 6;
    const int lane = threadIdx.x & 63;
    const int type = bid >> 10;
    const int row = bid & 1023;
    const float* tr = tL + (size_t)row * TOTAL;
    const float* sr = sL + (size_t)row * TOTAL;

    float kl = 0.f;

    if (type == 0) {                       // ---- g0 split across 2 waves ----
        uint32_t* kv = (uint32_t*)smem;            // 2*HQ*4 = 5632 B
        uint16_t* ix = (uint16_t*)(smem + 5632);   // 2*HQ*2 = 2816 B
        int c = half_compact(tr + w * 4096, w * 4096, kv + w * HQ, ix + w * HQ);
        if (lane == 0) cnts[w] = c;
        __syncthreads();
        if (w == 0)
            kl = pair_select(kv, ix, cnts, tr, sr);
    } else if (type == 1) {                // ---- g1 | g2, independent ----
        if (w == 0) {
            float*    v1 = (float*)smem;               // 5120 B
            uint16_t* i1 = (uint16_t*)(smem + 5120);   // 2560 B
            kl = big_wave<16, 1280, 20>(tr + 8192, sr + 8192, 0.60f, v1, i1);
        } else {
            float*    v2 = (float*)(smem + 7680);      // 3072 B
            uint16_t* i2 = (uint16_t*)(smem + 10752);  // 1536 B
            kl = big_wave<8, 768, 12>(tr + 12288, sr + 12288, 0.50f, v2, i2);
        }
    } else {                               // ---- g3 | g4+tinies ----
        if (w == 0) {
            kl = mid_wave<16>(tr + 14336, sr + 14336);
        } else {
            kl  = mid_wave<8>(tr + 15360, sr + 15360);
            kl += tiny_group(tr + 15872, sr + 15872, 256);
            kl += tiny_group(tr + 16128, sr + 16128, 128);
            kl += tiny_group(tr + 16256, sr + 16256, 64);
            kl += tiny_group(tr + 16320, sr + 16320, 32);
            kl += tiny_group(tr + 16352, sr + 16352, 16);
        }
    }

    if (lane == 0)
        atomicAdd(&partial[(row + type * 21 + w * 37) & (NBUCKET - 1)],
                  kl * (0.1f / 1024.f));
}

__global__ void zero_ws(float* partial) {
    if (threadIdx.x < NBUCKET) partial[threadIdx.x] = 0.f;
}

__global__ void final_sum(const float* __restrict__ partial, float* __restrict__ out) {
    float v = (threadIdx.x < NBUCKET) ? partial[threadIdx.x] : 0.f;
    #pragma unroll
    for (int o = 32; o > 0; o >>= 1) v += __shfl_down(v, o, 64);
    if (threadIdx.x == 0) out[0] = v;
}

extern "C" void kernel_launch(void* const* d_in, const int* in_sizes, int n_in,
                              void* d_out, int out_size, void* d_ws, size_t ws_size,
                              hipStream_t stream) {
    (void)in_sizes; (void)n_in; (void)ws_size; (void)out_size;
    const float* s = (const float*)d_in[0];
    const float* t = (const float*)d_in[1];
    float* out = (float*)d_out;
    float* ws = (float*)d_ws;

    hipLaunchKernelGGL(zero_ws, dim3(1), dim3(64), 0, stream, ws);
    hipLaunchKernelGGL(kd_mix, dim3(3072), dim3(128), 0, stream, s, t, ws);
    hipLaunchKernelGGL(final_sum, dim3(1), dim3(64), 0, stream, ws, out);
}

// Round 14
// 166.807 us; speedup vs baseline: 1.0650x; 1.0650x over previous
//
#include <hip/hip_runtime.h>
#include <stdint.h>
#include <float.h>

#define TOTAL 16368
#define KSEL 500
#define HQ 704            // per-half g0 cap (4096 @ thr1.10: mean 556, +6.6sd)
#define NSH 22            // 2*HQ/64
#define NBUCKET 64

// order-preserving float<->uint key (monotonic increasing on finite floats)
__device__ __forceinline__ uint32_t fkey(float f) {
    uint32_t u = __float_as_uint(f);
    return (u & 0x80000000u) ? ~u : (u | 0x80000000u);
}
__device__ __forceinline__ float keyf(uint32_t k) {
    uint32_t u = (k & 0x80000000u) ? (k & 0x7FFFFFFFu) : ~k;
    return __uint_as_float(u);
}
__device__ __forceinline__ int lanerank(uint64_t m) {
    return __builtin_amdgcn_mbcnt_hi((uint32_t)(m >> 32),
           __builtin_amdgcn_mbcnt_lo((uint32_t)m, 0));
}
__device__ __forceinline__ int wave_sumi(int v) {
    #pragma unroll
    for (int o = 32; o > 0; o >>= 1) v += __shfl_xor(v, o, 64);
    return v;
}
__device__ __forceinline__ float wave_sumf(float v) {
    #pragma unroll
    for (int o = 32; o > 0; o >>= 1) v += __shfl_xor(v, o, 64);
    return v;
}
__device__ __forceinline__ float wave_maxf(float v) {
    #pragma unroll
    for (int o = 32; o > 0; o >>= 1) v = fmaxf(v, __shfl_xor(v, o, 64));
    return v;
}
__device__ __forceinline__ void lse_merge(float& m, float& l, float m2, float l2) {
    float M = fmaxf(m, m2);
    l = l * __expf(m - M) + l2 * __expf(m2 - M);
    m = M;
}

// exact exhaustive fallback (never taken for N(0,1) bench data); returns kl on
// lane 0 (0 elsewhere). Bisection on 45-bit key (fkey<<13 | (8191-idx)).
__device__ __noinline__ float wave_slow_kl(const float* __restrict__ t,
                                           const float* __restrict__ s, int C) {
    const int lane = threadIdx.x & 63;
    uint64_t lo = 0ull, hi = (1ull << 45), tau = 0ull;
    int cl = C, ch = 0;
    #pragma unroll 1
    for (int it = 0; it < 100; ++it) {
        uint64_t span = hi - lo;
        if (span <= 1ull) { tau = lo; break; }
        uint64_t mid;
        if (it & 1) mid = lo + (span >> 1);
        else {
            uint64_t st = span * (uint64_t)(cl - KSEL) / (uint64_t)(cl - ch);
            if (st < 1) st = 1;
            if (st > span - 1) st = span - 1;
            mid = lo + st;
        }
        int c = 0;
        #pragma unroll 1
        for (int i = lane; i < C; i += 64) {
            uint64_t ck = ((uint64_t)fkey(t[i]) << 13) | (uint64_t)(8191 - i);
            c += (ck > mid);
        }
        c = wave_sumi(c);
        if (c == KSEL) { tau = mid; break; }
        if (c > KSEL) { lo = mid; cl = c; } else { hi = mid; ch = c; }
    }
    float tmx = -FLT_MAX;
    for (int i = lane; i < C; i += 64) tmx = fmaxf(tmx, t[i]);
    tmx = wave_maxf(tmx);
    float St = 0.f, Stt = 0.f, Sts = 0.f, sm = -FLT_MAX;
    #pragma unroll 1
    for (int i = lane; i < C; i += 64) {
        float x = t[i];
        uint64_t ck = ((uint64_t)fkey(x) << 13) | (uint64_t)(8191 - i);
        if (ck > tau) {
            float e = __expf(x - tmx), v = s[i];
            St += e; Stt += e * x; Sts += e * v;
            sm = fmaxf(sm, v);
        }
    }
    St = wave_sumf(St); Stt = wave_sumf(Stt); Sts = wave_sumf(Sts); sm = wave_maxf(sm);
    float Ss = 0.f;
    #pragma unroll 1
    for (int i = lane; i < C; i += 64) {
        uint64_t ck = ((uint64_t)fkey(t[i]) << 13) | (uint64_t)(8191 - i);
        if (ck > tau) Ss += __expf(s[i] - sm);
    }
    Ss = wave_sumf(Ss);
    if (lane == 0)
        return (Stt - Sts) / St - tmx - __logf(St) + sm + __logf(Ss);
    return 0.f;
}

// Big group in ONE wave (C = NF4*256), proven R10 late-gather path: teacher
// double-buffered stream; ballot compaction of (val,idx) to LDS; bisection on
// register keys; student gathered ONLY for selected slots. kl on lane 0.
template <int NF4, int CAPT, int NST>
__device__ float big_wave(const float* __restrict__ tg, const float* __restrict__ s,
                          float thr, float* vals, uint16_t* idxs) {
    const int lane = threadIdx.x & 63;
    const float4* t4 = (const float4*)tg;
    constexpr int NB = NF4 / 8;
    int cnt = 0;
    float4 buf[8], nxt[8];
    #pragma unroll
    for (int u = 0; u < 8; ++u) buf[u] = t4[u * 64 + lane];
    #pragma unroll 1
    for (int b = 0; b < NB; ++b) {
        if (b + 1 < NB) {
            #pragma unroll
            for (int u = 0; u < 8; ++u)
                nxt[u] = t4[((b + 1) * 8 + u) * 64 + lane];
        }
        #pragma unroll
        for (int u = 0; u < 8; ++u) {
            float xs[4] = {buf[u].x, buf[u].y, buf[u].z, buf[u].w};
            #pragma unroll
            for (int q = 0; q < 4; ++q) {
                bool p = xs[q] > thr;
                uint64_t m = __ballot(p);
                if (p) {
                    int ofs = cnt + lanerank(m);
                    if (ofs < CAPT) {
                        vals[ofs] = xs[q];
                        idxs[ofs] = (uint16_t)((((b * 8 + u) * 64 + lane) << 2) + q);
                    }
                }
                cnt += (int)__popcll(m);
            }
        }
        if (b + 1 < NB) {
            #pragma unroll
            for (int u = 0; u < 8; ++u) buf[u] = nxt[u];
        }
    }
    if (cnt < KSEL || cnt > CAPT) return wave_slow_kl(tg, s, NF4 * 256);

    uint32_t key[NST];
    #pragma unroll
    for (int j = 0; j < NST; ++j) {
        int p = lane + j * 64;
        key[j] = (p < cnt) ? fkey(vals[p]) : 0u;
    }
    uint32_t kmx = 0u, kmn = 0xFFFFFFFFu;
    #pragma unroll
    for (int j = 0; j < NST; ++j) {
        uint32_t k = key[j];
        kmx = k > kmx ? k : kmx;
        if (k) kmn = k < kmn ? k : kmn;
    }
    #pragma unroll
    for (int o = 32; o > 0; o >>= 1) {
        uint32_t a = __shfl_xor(kmx, o, 64); kmx = a > kmx ? a : kmx;
        uint32_t b2 = __shfl_xor(kmn, o, 64); kmn = b2 < kmn ? b2 : kmn;
    }
    const float tmax = keyf(kmx);

    uint32_t lo = kmn - 1u, hi = kmx, tauhi = kmx;
    int cl = cnt, ch = 0, cut = -1;
    bool exact = false;
    #pragma unroll 1
    for (int it = 0; it < 80; ++it) {
        uint32_t span = hi - lo;
        if (span <= 1u) break;
        uint32_t mid;
        if (!(it & 1)) {  // false position on empirical CDF
            uint64_t st = (uint64_t)span * (uint32_t)(cl - KSEL) / (uint32_t)(cl - ch);
            if (st < 1) st = 1;
            if (st > span - 1) st = span - 1;
            mid = lo + (uint32_t)st;
        } else mid = lo + (span >> 1);
        int c = 0;
        #pragma unroll
        for (int j = 0; j < NST; ++j)
            c += (int)__popcll(__ballot(key[j] > mid));
        if (c == KSEL) { tauhi = mid; exact = true; break; }
        if (c > KSEL) { lo = mid; cl = c; } else { hi = mid; ch = c; }
    }
    if (!exact) {
        tauhi = hi;
        const int nT = KSEL - ch, nTie = cl - ch;
        if (nT >= nTie) cut = 0x7FFFFFFF;
        else {
            int idxr[NST];
            #pragma unroll
            for (int j = 0; j < NST; ++j) {
                int p = lane + j * 64;
                idxr[j] = (p < cnt) ? (int)idxs[p] : 0x7FFF;
            }
            int l = -1, h = 8191;
            #pragma unroll 1
            while (h - l > 1) {
                int m = (l + h) >> 1;
                int c = 0;
                #pragma unroll
                for (int j = 0; j < NST; ++j)
                    c += (int)__popcll(__ballot(key[j] == tauhi && idxr[j] <= m));
                if (c >= nT) h = m; else l = m;
            }
            cut = h;
        }
    }

    uint32_t selm = 0u;
    if (cut == -1) {
        #pragma unroll
        for (int j = 0; j < NST; ++j) selm |= (key[j] > tauhi ? 1u : 0u) << j;
    } else if (cut == 0x7FFFFFFF) {
        #pragma unroll
        for (int j = 0; j < NST; ++j) selm |= (key[j] >= tauhi ? 1u : 0u) << j;
    } else {
        #pragma unroll
        for (int j = 0; j < NST; ++j) {
            int p = lane + j * 64;
            bool sj = (key[j] > tauhi) ||
                      (key[j] == tauhi && p < cnt && (int)idxs[p] <= cut);
            selm |= (sj ? 1u : 0u) << j;
        }
    }

    float svc[NST];
    #pragma unroll
    for (int j = 0; j < NST; ++j)
        svc[j] = (selm & (1u << j)) ? s[(int)idxs[lane + j * 64]] : 0.f;

    float St = 0.f, Stt = 0.f, Sts = 0.f, sm = -FLT_MAX;
    #pragma unroll
    for (int j = 0; j < NST; ++j) {
        if (selm & (1u << j)) {
            float tv = keyf(key[j]);
            float e = __expf(tv - tmax);
            St += e; Stt += e * tv; Sts += e * svc[j];
            sm = fmaxf(sm, svc[j]);
        }
    }
    #pragma unroll
    for (int o = 32; o > 0; o >>= 1) {
        St  += __shfl_xor(St,  o, 64);
        Stt += __shfl_xor(Stt, o, 64);
        Sts += __shfl_xor(Sts, o, 64);
        sm = fmaxf(sm, __shfl_xor(sm, o, 64));
    }
    float Ss = 0.f;
    #pragma unroll
    for (int j = 0; j < NST; ++j)
        if (selm & (1u << j)) Ss += __expf(svc[j] - sm);
    Ss = wave_sumf(Ss);
    if (lane == 0)
        return (Stt - Sts) / St - tmax - __logf(St) + sm + __logf(Ss);
    return 0.f;
}

// g0 half (4096 floats) in one wave: R10's compaction loop (NF4=16) writing
// (fkey, group-global idx) into this wave's PRIVATE HQ-slot LDS segment.
__device__ int half_compact(const float* __restrict__ tq, int idx_off,
                            uint32_t* kv, uint16_t* ix) {
    const int lane = threadIdx.x & 63;
    const float4* t4 = (const float4*)tq;
    int cnt = 0;
    float4 buf[8], nxt[8];
    #pragma unroll
    for (int u = 0; u < 8; ++u) buf[u] = t4[u * 64 + lane];
    #pragma unroll 1
    for (int b = 0; b < 2; ++b) {
        if (b == 0) {
            #pragma unroll
            for (int u = 0; u < 8; ++u) nxt[u] = t4[(8 + u) * 64 + lane];
        }
        #pragma unroll
        for (int u = 0; u < 8; ++u) {
            float xs[4] = {buf[u].x, buf[u].y, buf[u].z, buf[u].w};
            #pragma unroll
            for (int q = 0; q < 4; ++q) {
                bool p = xs[q] > 1.10f;
                uint64_t m = __ballot(p);
                if (p) {
                    int ofs = cnt + lanerank(m);
                    if (ofs < HQ) {
                        kv[ofs] = fkey(xs[q]);
                        ix[ofs] = (uint16_t)(((((b * 8 + u) * 64 + lane) << 2) + q)
                                             + idx_off);
                    }
                }
                cnt += (int)__popcll(m);
            }
        }
        if (b == 0) {
            #pragma unroll
            for (int u = 0; u < 8; ++u) buf[u] = nxt[u];
        }
    }
    if (cnt <= HQ)
        for (int p = cnt + lane; p < HQ; p += 64) kv[p] = 0u;  // pad unselectable
    return cnt;
}

// g0 select over the 2 LDS half-segments (keys to regs, ballot bisection,
// LATE student gather for selected slots only). Returns kl on lane 0.
__device__ float pair_select(const uint32_t* __restrict__ kv,
                             const uint16_t* __restrict__ ix,
                             const int* __restrict__ cnts,
                             const float* __restrict__ tg,
                             const float* __restrict__ sg) {
    const int lane = threadIdx.x & 63;
    const int tot = cnts[0] + cnts[1];
    if (cnts[0] > HQ || cnts[1] > HQ || tot < KSEL)
        return wave_slow_kl(tg, sg, 8192);

    uint32_t key[NSH];
    #pragma unroll
    for (int j = 0; j < NSH; ++j) key[j] = kv[lane + j * 64];

    uint32_t kmx = 0u, kmn = 0xFFFFFFFFu;
    #pragma unroll
    for (int j = 0; j < NSH; ++j) {
        uint32_t k = key[j];
        kmx = k > kmx ? k : kmx;
        if (k) kmn = k < kmn ? k : kmn;
    }
    #pragma unroll
    for (int o = 32; o > 0; o >>= 1) {
        uint32_t a = __shfl_xor(kmx, o, 64); kmx = a > kmx ? a : kmx;
        uint32_t b2 = __shfl_xor(kmn, o, 64); kmn = b2 < kmn ? b2 : kmn;
    }
    const float tmax = keyf(kmx);

    uint32_t lo = kmn - 1u, hi = kmx, tauhi = kmx;
    int cl = tot, ch = 0, cut = -1;
    bool exact = false;
    #pragma unroll 1
    for (int it = 0; it < 80; ++it) {
        uint32_t span = hi - lo;
        if (span <= 1u) break;
        uint32_t mid;
        if (!(it & 1)) {  // false position on empirical CDF
            uint64_t st = (uint64_t)span * (uint32_t)(cl - KSEL) / (uint32_t)(cl - ch);
            if (st < 1) st = 1;
            if (st > span - 1) st = span - 1;
            mid = lo + (uint32_t)st;
        } else mid = lo + (span >> 1);
        int c = 0;
        #pragma unroll
        for (int j = 0; j < NSH; ++j)
            c += (int)__popcll(__ballot(key[j] > mid));
        if (c == KSEL) { tauhi = mid; exact = true; break; }
        if (c > KSEL) { lo = mid; cl = c; } else { hi = mid; ch = c; }
    }
    if (!exact) {
        tauhi = hi;
        const int nT = KSEL - ch, nTie = cl - ch;
        if (nT >= nTie) cut = 0x7FFFFFFF;
        else {  // padded keys are 0 != tauhi, so garbage ix never counted
            int l = -1, h = 8191;
            #pragma unroll 1
            while (h - l > 1) {
                int m = (l + h) >> 1;
                int c = 0;
                #pragma unroll
                for (int j = 0; j < NSH; ++j)
                    c += (int)__popcll(__ballot(key[j] == tauhi &&
                                                (int)ix[lane + j * 64] <= m));
                if (c >= nT) h = m; else l = m;
            }
            cut = h;
        }
    }

    uint32_t selm = 0u;
    if (cut == -1) {
        #pragma unroll
        for (int j = 0; j < NSH; ++j) selm |= (key[j] > tauhi ? 1u : 0u) << j;
    } else if (cut == 0x7FFFFFFF) {
        #pragma unroll
        for (int j = 0; j < NSH; ++j) selm |= (key[j] >= tauhi ? 1u : 0u) << j;
    } else {
        #pragma unroll
        for (int j = 0; j < NSH; ++j) {
            bool sj = (key[j] > tauhi) ||
                      (key[j] == tauhi && (int)ix[lane + j * 64] <= cut);
            selm |= (sj ? 1u : 0u) << j;
        }
    }

    float svc[NSH];
    #pragma unroll
    for (int j = 0; j < NSH; ++j)
        svc[j] = (selm & (1u << j)) ? sg[(int)ix[lane + j * 64]] : 0.f;

    float St = 0.f, Stt = 0.f, Sts = 0.f, sm = -FLT_MAX;
    #pragma unroll
    for (int j = 0; j < NSH; ++j) {
        if (selm & (1u << j)) {
            float tv = keyf(key[j]);
            float e = __expf(tv - tmax);
            St += e; Stt += e * tv; Sts += e * svc[j];
            sm = fmaxf(sm, svc[j]);
        }
    }
    #pragma unroll
    for (int o = 32; o > 0; o >>= 1) {
        St  += __shfl_xor(St,  o, 64);
        Stt += __shfl_xor(Stt, o, 64);
        Sts += __shfl_xor(Sts, o, 64);
        sm = fmaxf(sm, __shfl_xor(sm, o, 64));
    }
    float Ss = 0.f;
    #pragma unroll
    for (int j = 0; j < NSH; ++j)
        if (selm & (1u << j)) Ss += __expf(svc[j] - sm);
    Ss = wave_sumf(Ss);
    if (lane == 0)
        return (Stt - Sts) / St - tmax - __logf(St) + sm + __logf(Ss);
    return 0.f;
}

// Exact top-KSEL + KL on dense register-resident keys, BALLOT bisection.
template <int NS, class IdxF>
__device__ float select_accum(uint32_t (&key)[NS], IdxF idxOf, const float* svp) {
    const int lane = threadIdx.x & 63;
    uint32_t kmx = 0u, kmn = 0xFFFFFFFFu;
    #pragma unroll
    for (int j = 0; j < NS; ++j) {
        uint32_t k = key[j];
        kmx = k > kmx ? k : kmx;
        kmn = k < kmn ? k : kmn;
    }
    #pragma unroll
    for (int o = 32; o > 0; o >>= 1) {
        uint32_t a = __shfl_xor(kmx, o, 64); kmx = a > kmx ? a : kmx;
        uint32_t b = __shfl_xor(kmn, o, 64); kmn = b < kmn ? b : kmn;
    }
    const float tmax = keyf(kmx);

    uint32_t lo = kmn - 1u, hi = kmx, tauhi = kmx;
    int cl = NS * 64, ch = 0, cut = -1;
    bool exact = false;
    #pragma unroll 1
    for (int it = 0; it < 80; ++it) {
        uint32_t span = hi - lo;
        if (span <= 1u) break;
        uint32_t mid;
        if (!(it & 1)) {
            uint64_t st = (uint64_t)span * (uint32_t)(cl - KSEL) / (uint32_t)(cl - ch);
            if (st < 1) st = 1;
            if (st > span - 1) st = span - 1;
            mid = lo + (uint32_t)st;
        } else mid = lo + (span >> 1);
        int c = 0;
        #pragma unroll
        for (int j = 0; j < NS; ++j)
            c += (int)__popcll(__ballot(key[j] > mid));
        if (c == KSEL) { tauhi = mid; exact = true; break; }
        if (c > KSEL) { lo = mid; cl = c; } else { hi = mid; ch = c; }
    }
    if (!exact) {
        tauhi = hi;
        const int nT = KSEL - ch, nTie = cl - ch;
        if (nT >= nTie) cut = 0x7FFFFFFF;
        else {
            int l = -1, h = NS * 64 - 1;
            #pragma unroll 1
            while (h - l > 1) {
                int m = (l + h) >> 1;
                int c = 0;
                #pragma unroll
                for (int j = 0; j < NS; ++j)
                    c += (int)__popcll(__ballot(key[j] == tauhi && idxOf(j) <= m));
                if (c >= nT) h = m; else l = m;
            }
            cut = h;
        }
    }

    float St = 0.f, Stt = 0.f, Sts = 0.f, sm = -FLT_MAX;
    #pragma unroll
    for (int j = 0; j < NS; ++j) {
        uint32_t kj = key[j];
        bool sj = (kj > tauhi) || (kj == tauhi && idxOf(j) <= cut);
        if (sj) {
            float tv = keyf(kj);
            float e = __expf(tv - tmax);
            St += e; Stt += e * tv; Sts += e * svp[j];
            sm = fmaxf(sm, svp[j]);
        }
    }
    #pragma unroll
    for (int o = 32; o > 0; o >>= 1) {
        St  += __shfl_xor(St,  o, 64);
        Stt += __shfl_xor(Stt, o, 64);
        Sts += __shfl_xor(Sts, o, 64);
        sm = fmaxf(sm, __shfl_xor(sm, o, 64));
    }
    float Ss = 0.f;
    #pragma unroll
    for (int j = 0; j < NS; ++j) {
        uint32_t kj = key[j];
        bool sj = (kj > tauhi) || (kj == tauhi && idxOf(j) <= cut);
        if (sj) Ss += __expf(svp[j] - sm);
    }
    Ss = wave_sumf(Ss);
    if (lane == 0)
        return (Stt - Sts) / St - tmax - __logf(St) + sm + __logf(Ss);
    return 0.f;
}

// mid groups (C = NJ*64): whole group + student prefetched to registers
template <int NJ>
__device__ float mid_wave(const float* __restrict__ t, const float* __restrict__ s) {
    const int lane = threadIdx.x & 63;
    const float4* t4 = (const float4*)t;
    const float4* s4 = (const float4*)s;
    uint32_t key[NJ];
    float svp[NJ];
    #pragma unroll
    for (int c = 0; c < NJ / 4; ++c) {
        float4 x = t4[lane + c * 64];
        float4 y = s4[lane + c * 64];
        key[4 * c + 0] = fkey(x.x); key[4 * c + 1] = fkey(x.y);
        key[4 * c + 2] = fkey(x.z); key[4 * c + 3] = fkey(x.w);
        svp[4 * c + 0] = y.x; svp[4 * c + 1] = y.y;
        svp[4 * c + 2] = y.z; svp[4 * c + 3] = y.w;
    }
    auto idxOf = [&](int j) { return ((lane + (j >> 2) * 64) << 2) + (j & 3); };
    return select_accum<NJ>(key, idxOf, svp);
}

// tiny groups (k == C <= 256): whole-group softmax; returns kl on lane 0
__device__ float tiny_group(const float* __restrict__ t, const float* __restrict__ s,
                            int Cg) {
    const int lane = threadIdx.x & 63;
    float St = 0.f, Stt = 0.f, Sts = 0.f, m = -FLT_MAX, l = 0.f;
    float tv[4], svv[4];
    #pragma unroll
    for (int q = 0; q < 4; ++q) {
        int i = lane + q * 64;
        bool va = i < Cg;
        tv[q] = va ? t[i] : -FLT_MAX;
        svv[q] = va ? s[i] : 0.f;
    }
    float mx = -FLT_MAX;
    #pragma unroll
    for (int q = 0; q < 4; ++q) mx = fmaxf(mx, tv[q]);
    mx = wave_maxf(mx);
    #pragma unroll
    for (int q = 0; q < 4; ++q) {
        if (lane + q * 64 < Cg) {
            float e = __expf(tv[q] - mx);
            St += e; Stt += e * tv[q]; Sts += e * svv[q];
            float x = svv[q];
            if (x > m) { l = l * __expf(m - x) + 1.f; m = x; }
            else       { l += __expf(x - m); }
        }
    }
    #pragma unroll
    for (int o = 32; o > 0; o >>= 1) {
        St  += __shfl_xor(St,  o, 64);
        Stt += __shfl_xor(Stt, o, 64);
        Sts += __shfl_xor(Sts, o, 64);
        float m2 = __shfl_xor(m, o, 64);
        float l2 = __shfl_xor(l, o, 64);
        lse_merge(m, l, m2, l2);
    }
    if (lane == 0)
        return (Stt - Sts) / St - mx - __logf(St) + m + __logf(l);
    return 0.f;
}

// 3072 blocks x 128 threads (2 waves). __launch_bounds__(128, 4): VGPR budget
// 128 so pair_select's key[22]+svc[22] stay in registers (R13's (128,6) capped
// at ~40 VGPR and spilled 11.4 MB to scratch -> the entire regression).
//  A (bid<1024):       w0/w1 = g0 halves (32KB each, identical -> convoy ~0);
//                      one __syncthreads; w0 selects (late-gather).
//  B (1024..2047):     w0 = g1, w1 = g2 (independent, no barrier).
//  C (2048..3071):     w0 = g3, w1 = g4 + tinies (independent, no barrier).
__global__ __launch_bounds__(128, 4) void kd_mix(const float* __restrict__ sL,
                                                 const float* __restrict__ tL,
                                                 float* __restrict__ partial) {
    __shared__ char smem[12544] __attribute__((aligned(16)));
    __shared__ int cnts[2];
    const int bid = blockIdx.x;
    const int w = threadIdx.x >> 6;
    const int lane = threadIdx.x & 63;
    const int type = bid >> 10;
    const int row = bid & 1023;
    const float* tr = tL + (size_t)row * TOTAL;
    const float* sr = sL + (size_t)row * TOTAL;

    float kl = 0.f;

    if (type == 0) {                       // ---- g0 split across 2 waves ----
        uint32_t* kv = (uint32_t*)smem;            // 2*HQ*4 = 5632 B
        uint16_t* ix = (uint16_t*)(smem + 5632);   // 2*HQ*2 = 2816 B
        int c = half_compact(tr + w * 4096, w * 4096, kv + w * HQ, ix + w * HQ);
        if (lane == 0) cnts[w] = c;
        __syncthreads();
        if (w == 0)
            kl = pair_select(kv, ix, cnts, tr, sr);
    } else if (type == 1) {                // ---- g1 | g2, independent ----
        if (w == 0) {
            float*    v1 = (float*)smem;               // 5120 B
            uint16_t* i1 = (uint16_t*)(smem + 5120);   // 2560 B
            kl = big_wave<16, 1280, 20>(tr + 8192, sr + 8192, 0.60f, v1, i1);
        } else {
            float*    v2 = (float*)(smem + 7680);      // 3072 B
            uint16_t* i2 = (uint16_t*)(smem + 10752);  // 1536 B
            kl = big_wave<8, 768, 12>(tr + 12288, sr + 12288, 0.50f, v2, i2);
        }
    } else {                               // ---- g3 | g4+tinies ----
        if (w == 0) {
            kl = mid_wave<16>(tr + 14336, sr + 14336);
        } else {
            kl  = mid_wave<8>(tr + 15360, sr + 15360);
            kl += tiny_group(tr + 15872, sr + 15872, 256);
            kl += tiny_group(tr + 16128, sr + 16128, 128);
            kl += tiny_group(tr + 16256, sr + 16256, 64);
            kl += tiny_group(tr + 16320, sr + 16320, 32);
            kl += tiny_group(tr + 16352, sr + 16352, 16);
        }
    }

    if (lane == 0)
        atomicAdd(&partial[(row + type * 21 + w * 37) & (NBUCKET - 1)],
                  kl * (0.1f / 1024.f));
}

__global__ void zero_ws(float* partial) {
    if (threadIdx.x < NBUCKET) partial[threadIdx.x] = 0.f;
}

__global__ void final_sum(const float* __restrict__ partial, float* __restrict__ out) {
    float v = (threadIdx.x < NBUCKET) ? partial[threadIdx.x] : 0.f;
    #pragma unroll
    for (int o = 32; o > 0; o >>= 1) v += __shfl_down(v, o, 64);
    if (threadIdx.x == 0) out[0] = v;
}

extern "C" void kernel_launch(void* const* d_in, const int* in_sizes, int n_in,
                              void* d_out, int out_size, void* d_ws, size_t ws_size,
                              hipStream_t stream) {
    (void)in_sizes; (void)n_in; (void)ws_size; (void)out_size;
    const float* s = (const float*)d_in[0];
    const float* t = (const float*)d_in[1];
    float* out = (float*)d_out;
    float* ws = (float*)d_ws;

    hipLaunchKernelGGL(zero_ws, dim3(1), dim3(64), 0, stream, ws);
    hipLaunchKernelGGL(kd_mix, dim3(3072), dim3(128), 0, stream, s, t, ws);
    hipLaunchKernelGGL(final_sum, dim3(1), dim3(64), 0, stream, ws, out);
}

// Round 15
// 164.324 us; speedup vs baseline: 1.0811x; 1.0151x over previous
//
#include <hip/hip_runtime.h>
#include <stdint.h>
#include <float.h>

#define TOTAL 16368
#define KSEL 500
#define CAP 896           // candidate cap; thresholds target E[cnt]~700 (7.7+ sigma margins)
#define NSLOT 14          // CAP / 64
#define NBUCKET 64

// order-preserving float<->uint key (monotonic increasing on finite floats)
__device__ __forceinline__ uint32_t fkey(float f) {
    uint32_t u = __float_as_uint(f);
    return (u & 0x80000000u) ? ~u : (u | 0x80000000u);
}
__device__ __forceinline__ float keyf(uint32_t k) {
    uint32_t u = (k & 0x80000000u) ? (k & 0x7FFFFFFFu) : ~k;
    return __uint_as_float(u);
}
__device__ __forceinline__ int lanerank(uint64_t m) {
    return __builtin_amdgcn_mbcnt_hi((uint32_t)(m >> 32),
           __builtin_amdgcn_mbcnt_lo((uint32_t)m, 0));
}
__device__ __forceinline__ int wave_sumi(int v) {
    #pragma unroll
    for (int o = 32; o > 0; o >>= 1) v += __shfl_xor(v, o, 64);
    return v;
}
__device__ __forceinline__ float wave_sumf(float v) {
    #pragma unroll
    for (int o = 32; o > 0; o >>= 1) v += __shfl_xor(v, o, 64);
    return v;
}
__device__ __forceinline__ float wave_maxf(float v) {
    #pragma unroll
    for (int o = 32; o > 0; o >>= 1) v = fmaxf(v, __shfl_xor(v, o, 64));
    return v;
}
__device__ __forceinline__ void lse_merge(float& m, float& l, float m2, float l2) {
    float M = fmaxf(m, m2);
    l = l * __expf(m - M) + l2 * __expf(m2 - M);
    m = M;
}

// exact exhaustive fallback (never taken for N(0,1) bench data); returns kl on
// lane 0 (0 elsewhere). Bisection on 45-bit key (fkey<<13 | (8191-idx)).
__device__ __noinline__ float wave_slow_kl(const float* __restrict__ t,
                                           const float* __restrict__ s, int C) {
    const int lane = threadIdx.x & 63;
    uint64_t lo = 0ull, hi = (1ull << 45), tau = 0ull;
    int cl = C, ch = 0;
    #pragma unroll 1
    for (int it = 0; it < 100; ++it) {
        uint64_t span = hi - lo;
        if (span <= 1ull) { tau = lo; break; }
        uint64_t mid;
        if (it & 1) mid = lo + (span >> 1);
        else {
            uint64_t st = span * (uint64_t)(cl - KSEL) / (uint64_t)(cl - ch);
            if (st < 1) st = 1;
            if (st > span - 1) st = span - 1;
            mid = lo + st;
        }
        int c = 0;
        #pragma unroll 1
        for (int i = lane; i < C; i += 64) {
            uint64_t ck = ((uint64_t)fkey(t[i]) << 13) | (uint64_t)(8191 - i);
            c += (ck > mid);
        }
        c = wave_sumi(c);
        if (c == KSEL) { tau = mid; break; }
        if (c > KSEL) { lo = mid; cl = c; } else { hi = mid; ch = c; }
    }
    float tmx = -FLT_MAX;
    for (int i = lane; i < C; i += 64) tmx = fmaxf(tmx, t[i]);
    tmx = wave_maxf(tmx);
    float St = 0.f, Stt = 0.f, Sts = 0.f, sm = -FLT_MAX;
    #pragma unroll 1
    for (int i = lane; i < C; i += 64) {
        float x = t[i];
        uint64_t ck = ((uint64_t)fkey(x) << 13) | (uint64_t)(8191 - i);
        if (ck > tau) {
            float e = __expf(x - tmx), v = s[i];
            St += e; Stt += e * x; Sts += e * v;
            sm = fmaxf(sm, v);
        }
    }
    St = wave_sumf(St); Stt = wave_sumf(Stt); Sts = wave_sumf(Sts); sm = wave_maxf(sm);
    float Ss = 0.f;
    #pragma unroll 1
    for (int i = lane; i < C; i += 64) {
        uint64_t ck = ((uint64_t)fkey(t[i]) << 13) | (uint64_t)(8191 - i);
        if (ck > tau) Ss += __expf(s[i] - sm);
    }
    Ss = wave_sumf(Ss);
    if (lane == 0)
        return (Stt - Sts) / St - tmx - __logf(St) + sm + __logf(Ss);
    return 0.f;
}

// Big group in ONE wave (C = NF4*256), proven R10 late-gather path: teacher
// double-buffered stream; ballot compaction of (val,idx) to LDS; bisection on
// register keys; student gathered ONLY for selected slots. kl on lane 0.
template <int NF4>
__device__ float big_wave(const float* __restrict__ tg, const float* __restrict__ s,
                          float thr, float* vals, uint16_t* idxs) {
    const int lane = threadIdx.x & 63;
    const float4* t4 = (const float4*)tg;
    constexpr int NB = NF4 / 8;
    int cnt = 0;
    float4 buf[8], nxt[8];
    #pragma unroll
    for (int u = 0; u < 8; ++u) buf[u] = t4[u * 64 + lane];
    #pragma unroll 1
    for (int b = 0; b < NB; ++b) {
        if (b + 1 < NB) {
            #pragma unroll
            for (int u = 0; u < 8; ++u)
                nxt[u] = t4[((b + 1) * 8 + u) * 64 + lane];
        }
        #pragma unroll
        for (int u = 0; u < 8; ++u) {
            float xs[4] = {buf[u].x, buf[u].y, buf[u].z, buf[u].w};
            #pragma unroll
            for (int q = 0; q < 4; ++q) {
                bool p = xs[q] > thr;
                uint64_t m = __ballot(p);
                if (p) {
                    int ofs = cnt + lanerank(m);
                    if (ofs < CAP) {
                        vals[ofs] = xs[q];
                        idxs[ofs] = (uint16_t)((((b * 8 + u) * 64 + lane) << 2) + q);
                    }
                }
                cnt += (int)__popcll(m);
            }
        }
        if (b + 1 < NB) {
            #pragma unroll
            for (int u = 0; u < 8; ++u) buf[u] = nxt[u];
        }
    }
    if (cnt < KSEL || cnt > CAP) return wave_slow_kl(tg, s, NF4 * 256);

    // keys to regs (teacher only; NO student gather yet)
    uint32_t key[NSLOT];
    #pragma unroll
    for (int j = 0; j < NSLOT; ++j) {
        int p = lane + j * 64;
        key[j] = (p < cnt) ? fkey(vals[p]) : 0u;
    }
    uint32_t kmx = 0u, kmn = 0xFFFFFFFFu;
    #pragma unroll
    for (int j = 0; j < NSLOT; ++j) {
        uint32_t k = key[j];
        kmx = k > kmx ? k : kmx;
        if (k) kmn = k < kmn ? k : kmn;
    }
    #pragma unroll
    for (int o = 32; o > 0; o >>= 1) {
        uint32_t a = __shfl_xor(kmx, o, 64); kmx = a > kmx ? a : kmx;
        uint32_t b2 = __shfl_xor(kmn, o, 64); kmn = b2 < kmn ? b2 : kmn;
    }
    const float tmax = keyf(kmx);

    uint32_t lo = kmn - 1u, hi = kmx, tauhi = kmx;
    int cl = cnt, ch = 0, cut = -1;
    bool exact = false;
    #pragma unroll 1
    for (int it = 0; it < 80; ++it) {
        uint32_t span = hi - lo;
        if (span <= 1u) break;
        uint32_t mid;
        if (!(it & 1)) {  // false position on empirical CDF
            uint64_t st = (uint64_t)span * (uint32_t)(cl - KSEL) / (uint32_t)(cl - ch);
            if (st < 1) st = 1;
            if (st > span - 1) st = span - 1;
            mid = lo + (uint32_t)st;
        } else mid = lo + (span >> 1);
        int c = 0;
        #pragma unroll
        for (int j = 0; j < NSLOT; ++j)
            c += (int)__popcll(__ballot(key[j] > mid));
        if (c == KSEL) { tauhi = mid; exact = true; break; }
        if (c > KSEL) { lo = mid; cl = c; } else { hi = mid; ch = c; }
    }
    if (!exact) {
        tauhi = hi;
        const int nT = KSEL - ch, nTie = cl - ch;
        if (nT >= nTie) cut = 0x7FFFFFFF;
        else {  // lowest-index tie-break; idx from LDS (rare path)
            int idxr[NSLOT];
            #pragma unroll
            for (int j = 0; j < NSLOT; ++j) {
                int p = lane + j * 64;
                idxr[j] = (p < cnt) ? (int)idxs[p] : 0x7FFF;
            }
            int l = -1, h = 8191;
            #pragma unroll 1
            while (h - l > 1) {
                int m = (l + h) >> 1;
                int c = 0;
                #pragma unroll
                for (int j = 0; j < NSLOT; ++j)
                    c += (int)__popcll(__ballot(key[j] == tauhi && idxr[j] <= m));
                if (c >= nT) h = m; else l = m;
            }
            cut = h;
        }
    }

    uint32_t selm = 0u;
    if (cut == -1) {
        #pragma unroll
        for (int j = 0; j < NSLOT; ++j) selm |= (key[j] > tauhi ? 1u : 0u) << j;
    } else if (cut == 0x7FFFFFFF) {
        #pragma unroll
        for (int j = 0; j < NSLOT; ++j) selm |= (key[j] >= tauhi ? 1u : 0u) << j;
    } else {
        #pragma unroll
        for (int j = 0; j < NSLOT; ++j) {
            int p = lane + j * 64;
            bool sj = (key[j] > tauhi) ||
                      (key[j] == tauhi && p < cnt && (int)idxs[p] <= cut);
            selm |= (sj ? 1u : 0u) << j;
        }
    }

    // LATE student gather: only the selected ~KSEL slots (batched; one drain)
    float svc[NSLOT];
    #pragma unroll
    for (int j = 0; j < NSLOT; ++j)
        svc[j] = (selm & (1u << j)) ? s[(int)idxs[lane + j * 64]] : 0.f;

    float St = 0.f, Stt = 0.f, Sts = 0.f, sm = -FLT_MAX;
    #pragma unroll
    for (int j = 0; j < NSLOT; ++j) {
        if (selm & (1u << j)) {
            float tv = keyf(key[j]);
            float e = __expf(tv - tmax);
            St += e; Stt += e * tv; Sts += e * svc[j];
            sm = fmaxf(sm, svc[j]);
        }
    }
    #pragma unroll
    for (int o = 32; o > 0; o >>= 1) {
        St  += __shfl_xor(St,  o, 64);
        Stt += __shfl_xor(Stt, o, 64);
        Sts += __shfl_xor(Sts, o, 64);
        sm = fmaxf(sm, __shfl_xor(sm, o, 64));
    }
    float Ss = 0.f;
    #pragma unroll
    for (int j = 0; j < NSLOT; ++j)
        if (selm & (1u << j)) Ss += __expf(svc[j] - sm);
    Ss = wave_sumf(Ss);
    if (lane == 0)
        return (Stt - Sts) / St - tmax - __logf(St) + sm + __logf(Ss);
    return 0.f;
}

// Exact top-KSEL + KL on dense register-resident keys, BALLOT bisection.
template <int NS, class IdxF>
__device__ float select_accum(uint32_t (&key)[NS], IdxF idxOf, const float* svp) {
    const int lane = threadIdx.x & 63;
    uint32_t kmx = 0u, kmn = 0xFFFFFFFFu;
    #pragma unroll
    for (int j = 0; j < NS; ++j) {
        uint32_t k = key[j];
        kmx = k > kmx ? k : kmx;
        kmn = k < kmn ? k : kmn;
    }
    #pragma unroll
    for (int o = 32; o > 0; o >>= 1) {
        uint32_t a = __shfl_xor(kmx, o, 64); kmx = a > kmx ? a : kmx;
        uint32_t b = __shfl_xor(kmn, o, 64); kmn = b < kmn ? b : kmn;
    }
    const float tmax = keyf(kmx);

    uint32_t lo = kmn - 1u, hi = kmx, tauhi = kmx;
    int cl = NS * 64, ch = 0, cut = -1;
    bool exact = false;
    #pragma unroll 1
    for (int it = 0; it < 80; ++it) {
        uint32_t span = hi - lo;
        if (span <= 1u) break;
        uint32_t mid;
        if (!(it & 1)) {
            uint64_t st = (uint64_t)span * (uint32_t)(cl - KSEL) / (uint32_t)(cl - ch);
            if (st < 1) st = 1;
            if (st > span - 1) st = span - 1;
            mid = lo + (uint32_t)st;
        } else mid = lo + (span >> 1);
        int c = 0;
        #pragma unroll
        for (int j = 0; j < NS; ++j)
            c += (int)__popcll(__ballot(key[j] > mid));
        if (c == KSEL) { tauhi = mid; exact = true; break; }
        if (c > KSEL) { lo = mid; cl = c; } else { hi = mid; ch = c; }
    }
    if (!exact) {
        tauhi = hi;
        const int nT = KSEL - ch, nTie = cl - ch;
        if (nT >= nTie) cut = 0x7FFFFFFF;
        else {
            int l = -1, h = NS * 64 - 1;
            #pragma unroll 1
            while (h - l > 1) {
                int m = (l + h) >> 1;
                int c = 0;
                #pragma unroll
                for (int j = 0; j < NS; ++j)
                    c += (int)__popcll(__ballot(key[j] == tauhi && idxOf(j) <= m));
                if (c >= nT) h = m; else l = m;
            }
            cut = h;
        }
    }

    float St = 0.f, Stt = 0.f, Sts = 0.f, sm = -FLT_MAX;
    #pragma unroll
    for (int j = 0; j < NS; ++j) {
        uint32_t kj = key[j];
        bool sj = (kj > tauhi) || (kj == tauhi && idxOf(j) <= cut);
        if (sj) {
            float tv = keyf(kj);
            float e = __expf(tv - tmax);
            St += e; Stt += e * tv; Sts += e * svp[j];
            sm = fmaxf(sm, svp[j]);
        }
    }
    #pragma unroll
    for (int o = 32; o > 0; o >>= 1) {
        St  += __shfl_xor(St,  o, 64);
        Stt += __shfl_xor(Stt, o, 64);
        Sts += __shfl_xor(Sts, o, 64);
        sm = fmaxf(sm, __shfl_xor(sm, o, 64));
    }
    float Ss = 0.f;
    #pragma unroll
    for (int j = 0; j < NS; ++j) {
        uint32_t kj = key[j];
        bool sj = (kj > tauhi) || (kj == tauhi && idxOf(j) <= cut);
        if (sj) Ss += __expf(svp[j] - sm);
    }
    Ss = wave_sumf(Ss);
    if (lane == 0)
        return (Stt - Sts) / St - tmax - __logf(St) + sm + __logf(Ss);
    return 0.f;
}

// mid groups (C = NJ*64): whole group + student prefetched to registers
template <int NJ>
__device__ float mid_wave(const float* __restrict__ t, const float* __restrict__ s) {
    const int lane = threadIdx.x & 63;
    const float4* t4 = (const float4*)t;
    const float4* s4 = (const float4*)s;
    uint32_t key[NJ];
    float svp[NJ];
    #pragma unroll
    for (int c = 0; c < NJ / 4; ++c) {
        float4 x = t4[lane + c * 64];
        float4 y = s4[lane + c * 64];
        key[4 * c + 0] = fkey(x.x); key[4 * c + 1] = fkey(x.y);
        key[4 * c + 2] = fkey(x.z); key[4 * c + 3] = fkey(x.w);
        svp[4 * c + 0] = y.x; svp[4 * c + 1] = y.y;
        svp[4 * c + 2] = y.z; svp[4 * c + 3] = y.w;
    }
    auto idxOf = [&](int j) { return ((lane + (j >> 2) * 64) << 2) + (j & 3); };
    return select_accum<NJ>(key, idxOf, svp);
}

// tiny groups (k == C <= 256): whole-group softmax; returns kl on lane 0
__device__ float tiny_group(const float* __restrict__ t, const float* __restrict__ s,
                            int Cg) {
    const int lane = threadIdx.x & 63;
    float St = 0.f, Stt = 0.f, Sts = 0.f, m = -FLT_MAX, l = 0.f;
    float tv[4], svv[4];
    #pragma unroll
    for (int q = 0; q < 4; ++q) {
        int i = lane + q * 64;
        bool va = i < Cg;
        tv[q] = va ? t[i] : -FLT_MAX;
        svv[q] = va ? s[i] : 0.f;
    }
    float mx = -FLT_MAX;
    #pragma unroll
    for (int q = 0; q < 4; ++q) mx = fmaxf(mx, tv[q]);
    mx = wave_maxf(mx);
    #pragma unroll
    for (int q = 0; q < 4; ++q) {
        if (lane + q * 64 < Cg) {
            float e = __expf(tv[q] - mx);
            St += e; Stt += e * tv[q]; Sts += e * svv[q];
            float x = svv[q];
            if (x > m) { l = l * __expf(m - x) + 1.f; m = x; }
            else       { l += __expf(x - m); }
        }
    }
    #pragma unroll
    for (int o = 32; o > 0; o >>= 1) {
        St  += __shfl_xor(St,  o, 64);
        Stt += __shfl_xor(Stt, o, 64);
        Sts += __shfl_xor(Sts, o, 64);
        float m2 = __shfl_xor(m, o, 64);
        float l2 = __shfl_xor(l, o, 64);
        lse_merge(m, l, m2, l2);
    }
    if (lane == 0)
        return (Stt - Sts) / St - mx - __logf(St) + m + __logf(l);
    return 0.f;
}

// ONE WAVE = ONE BLOCK = ONE job; five job types (proven R10 structure):
//   job 0: g0 (8192)  job 1: g1 (4096)  job 2: g2 (2048)
//   job 3: g3 (1024)  job 4: g4 (512) + tinies
// OCCUPANCY push vs R10: CAP 1280->896 (raised thresholds, E[cnt]~700,
// 7.7+ sigma margins, exact fallback intact) cuts LDS 7.5->5.25 KB/block
// -> ~30 single-wave blocks/CU; __launch_bounds__(64,8) permits 8 waves/EU.
__global__ __launch_bounds__(64, 8) void kd_jobs(const float* __restrict__ sL,
                                                 const float* __restrict__ tL,
                                                 float* __restrict__ partial) {
    __shared__ float    vals[CAP];    // 3.5 KiB
    __shared__ uint16_t idxs[CAP];    // 1.75 KiB
    const int bid = blockIdx.x;
    const int job = bid >> 10;
    const int row = bid & 1023;
    const float* tr = tL + (size_t)row * TOTAL;
    const float* sr = sL + (size_t)row * TOTAL;

    float kl = 0.f;
    switch (job) {
    case 0:
        kl = big_wave<32>(tr, sr, 1.37f, vals, idxs);        // E[cnt]~700
        break;
    case 1:
        kl = big_wave<16>(tr + 8192, sr + 8192, 0.95f, vals, idxs);
        break;
    case 2:
        kl = big_wave<8>(tr + 12288, sr + 12288, 0.41f, vals, idxs);
        break;
    case 3:
        kl = mid_wave<16>(tr + 14336, sr + 14336);
        break;
    default:
        kl  = mid_wave<8>(tr + 15360, sr + 15360);
        kl += tiny_group(tr + 15872, sr + 15872, 256);
        kl += tiny_group(tr + 16128, sr + 16128, 128);
        kl += tiny_group(tr + 16256, sr + 16256, 64);
        kl += tiny_group(tr + 16320, sr + 16320, 32);
        kl += tiny_group(tr + 16352, sr + 16352, 16);
        break;
    }

    if ((threadIdx.x & 63) == 0)
        atomicAdd(&partial[(row + job * 37) & (NBUCKET - 1)], kl * (0.1f / 1024.f));
}

__global__ void zero_ws(float* partial) {
    if (threadIdx.x < NBUCKET) partial[threadIdx.x] = 0.f;
}

__global__ void final_sum(const float* __restrict__ partial, float* __restrict__ out) {
    float v = (threadIdx.x < NBUCKET) ? partial[threadIdx.x] : 0.f;
    #pragma unroll
    for (int o = 32; o > 0; o >>= 1) v += __shfl_down(v, o, 64);
    if (threadIdx.x == 0) out[0] = v;
}

extern "C" void kernel_launch(void* const* d_in, const int* in_sizes, int n_in,
                              void* d_out, int out_size, void* d_ws, size_t ws_size,
                              hipStream_t stream) {
    (void)in_sizes; (void)n_in; (void)ws_size; (void)out_size;
    const float* s = (const float*)d_in[0];
    const float* t = (const float*)d_in[1];
    float* out = (float*)d_out;
    float* ws = (float*)d_ws;

    hipLaunchKernelGGL(zero_ws, dim3(1), dim3(64), 0, stream, ws);
    hipLaunchKernelGGL(kd_jobs, dim3(5120), dim3(64), 0, stream, s, t, ws);
    hipLaunchKernelGGL(final_sum, dim3(1), dim3(64), 0, stream, ws, out);
}

// Round 16
// 160.416 us; speedup vs baseline: 1.1074x; 1.0244x over previous
//
#include <hip/hip_runtime.h>
#include <stdint.h>
#include <float.h>

#define TOTAL 16368
#define KSEL 500
#define CAP 1280          // candidate cap (g0 mean ~1112 +5.4sd; g1 ~1123; g2 ~632)
#define NSLOT 20          // CAP / 64
#define NBUCKET 64

// order-preserving float<->uint key (monotonic increasing on finite floats)
__device__ __forceinline__ uint32_t fkey(float f) {
    uint32_t u = __float_as_uint(f);
    return (u & 0x80000000u) ? ~u : (u | 0x80000000u);
}
__device__ __forceinline__ float keyf(uint32_t k) {
    uint32_t u = (k & 0x80000000u) ? (k & 0x7FFFFFFFu) : ~k;
    return __uint_as_float(u);
}
__device__ __forceinline__ int lanerank(uint64_t m) {
    return __builtin_amdgcn_mbcnt_hi((uint32_t)(m >> 32),
           __builtin_amdgcn_mbcnt_lo((uint32_t)m, 0));
}
__device__ __forceinline__ int wave_sumi(int v) {
    #pragma unroll
    for (int o = 32; o > 0; o >>= 1) v += __shfl_xor(v, o, 64);
    return v;
}
__device__ __forceinline__ float wave_sumf(float v) {
    #pragma unroll
    for (int o = 32; o > 0; o >>= 1) v += __shfl_xor(v, o, 64);
    return v;
}
__device__ __forceinline__ float wave_maxf(float v) {
    #pragma unroll
    for (int o = 32; o > 0; o >>= 1) v = fmaxf(v, __shfl_xor(v, o, 64));
    return v;
}
__device__ __forceinline__ void lse_merge(float& m, float& l, float m2, float l2) {
    float M = fmaxf(m, m2);
    l = l * __expf(m - M) + l2 * __expf(m2 - M);
    m = M;
}

// exact exhaustive fallback (never taken for N(0,1) bench data); returns kl on
// lane 0 (0 elsewhere). Bisection on 45-bit key (fkey<<13 | (8191-idx)).
__device__ __noinline__ float wave_slow_kl(const float* __restrict__ t,
                                           const float* __restrict__ s, int C) {
    const int lane = threadIdx.x & 63;
    uint64_t lo = 0ull, hi = (1ull << 45), tau = 0ull;
    int cl = C, ch = 0;
    #pragma unroll 1
    for (int it = 0; it < 100; ++it) {
        uint64_t span = hi - lo;
        if (span <= 1ull) { tau = lo; break; }
        uint64_t mid;
        if (it & 1) mid = lo + (span >> 1);
        else {
            uint64_t st = span * (uint64_t)(cl - KSEL) / (uint64_t)(cl - ch);
            if (st < 1) st = 1;
            if (st > span - 1) st = span - 1;
            mid = lo + st;
        }
        int c = 0;
        #pragma unroll 1
        for (int i = lane; i < C; i += 64) {
            uint64_t ck = ((uint64_t)fkey(t[i]) << 13) | (uint64_t)(8191 - i);
            c += (ck > mid);
        }
        c = wave_sumi(c);
        if (c == KSEL) { tau = mid; break; }
        if (c > KSEL) { lo = mid; cl = c; } else { hi = mid; ch = c; }
    }
    float tmx = -FLT_MAX;
    for (int i = lane; i < C; i += 64) tmx = fmaxf(tmx, t[i]);
    tmx = wave_maxf(tmx);
    float St = 0.f, Stt = 0.f, Sts = 0.f, sm = -FLT_MAX;
    #pragma unroll 1
    for (int i = lane; i < C; i += 64) {
        float x = t[i];
        uint64_t ck = ((uint64_t)fkey(x) << 13) | (uint64_t)(8191 - i);
        if (ck > tau) {
            float e = __expf(x - tmx), v = s[i];
            St += e; Stt += e * x; Sts += e * v;
            sm = fmaxf(sm, v);
        }
    }
    St = wave_sumf(St); Stt = wave_sumf(Stt); Sts = wave_sumf(Sts); sm = wave_maxf(sm);
    float Ss = 0.f;
    #pragma unroll 1
    for (int i = lane; i < C; i += 64) {
        uint64_t ck = ((uint64_t)fkey(t[i]) << 13) | (uint64_t)(8191 - i);
        if (ck > tau) Ss += __expf(s[i] - sm);
    }
    Ss = wave_sumf(Ss);
    if (lane == 0)
        return (Stt - Sts) / St - tmx - __logf(St) + sm + __logf(Ss);
    return 0.f;
}

// Big group in ONE wave (C = NF4*256), LATE-GATHER edition: teacher-only
// double-buffered stream; ballot compaction of (val,idx) to LDS; bisection on
// register keys; student gathered ONLY for the ~KSEL selected slots AFTER tau
// is known. Returns kl on lane 0.
template <int NF4>
__device__ float big_wave(const float* __restrict__ tg, const float* __restrict__ s,
                          float thr, float* vals, uint16_t* idxs) {
    const int lane = threadIdx.x & 63;
    const float4* t4 = (const float4*)tg;
    constexpr int NB = NF4 / 8;
    int cnt = 0;
    float4 buf[8], nxt[8];
    #pragma unroll
    for (int u = 0; u < 8; ++u) buf[u] = t4[u * 64 + lane];
    #pragma unroll 1
    for (int b = 0; b < NB; ++b) {
        if (b + 1 < NB) {
            #pragma unroll
            for (int u = 0; u < 8; ++u)
                nxt[u] = t4[((b + 1) * 8 + u) * 64 + lane];
        }
        #pragma unroll
        for (int u = 0; u < 8; ++u) {
            float xs[4] = {buf[u].x, buf[u].y, buf[u].z, buf[u].w};
            #pragma unroll
            for (int q = 0; q < 4; ++q) {
                bool p = xs[q] > thr;
                uint64_t m = __ballot(p);
                if (p) {
                    int ofs = cnt + lanerank(m);
                    if (ofs < CAP) {
                        vals[ofs] = xs[q];
                        idxs[ofs] = (uint16_t)((((b * 8 + u) * 64 + lane) << 2) + q);
                    }
                }
                cnt += (int)__popcll(m);
            }
        }
        if (b + 1 < NB) {
            #pragma unroll
            for (int u = 0; u < 8; ++u) buf[u] = nxt[u];
        }
    }
    if (cnt < KSEL || cnt > CAP) return wave_slow_kl(tg, s, NF4 * 256);

    // keys to regs (teacher only; NO student gather yet)
    uint32_t key[NSLOT];
    #pragma unroll
    for (int j = 0; j < NSLOT; ++j) {
        int p = lane + j * 64;
        key[j] = (p < cnt) ? fkey(vals[p]) : 0u;
    }
    uint32_t kmx = 0u, kmn = 0xFFFFFFFFu;
    #pragma unroll
    for (int j = 0; j < NSLOT; ++j) {
        uint32_t k = key[j];
        kmx = k > kmx ? k : kmx;
        if (k) kmn = k < kmn ? k : kmn;
    }
    #pragma unroll
    for (int o = 32; o > 0; o >>= 1) {
        uint32_t a = __shfl_xor(kmx, o, 64); kmx = a > kmx ? a : kmx;
        uint32_t b2 = __shfl_xor(kmn, o, 64); kmn = b2 < kmn ? b2 : kmn;
    }
    const float tmax = keyf(kmx);

    uint32_t lo = kmn - 1u, hi = kmx, tauhi = kmx;
    int cl = cnt, ch = 0, cut = -1;
    bool exact = false;
    #pragma unroll 1
    for (int it = 0; it < 80; ++it) {
        uint32_t span = hi - lo;
        if (span <= 1u) break;
        uint32_t mid;
        if (!(it & 1)) {  // false position on empirical CDF
            uint64_t st = (uint64_t)span * (uint32_t)(cl - KSEL) / (uint32_t)(cl - ch);
            if (st < 1) st = 1;
            if (st > span - 1) st = span - 1;
            mid = lo + (uint32_t)st;
        } else mid = lo + (span >> 1);
        int c = 0;
        #pragma unroll
        for (int j = 0; j < NSLOT; ++j)
            c += (int)__popcll(__ballot(key[j] > mid));
        if (c == KSEL) { tauhi = mid; exact = true; break; }
        if (c > KSEL) { lo = mid; cl = c; } else { hi = mid; ch = c; }
    }
    if (!exact) {
        tauhi = hi;
        const int nT = KSEL - ch, nTie = cl - ch;
        if (nT >= nTie) cut = 0x7FFFFFFF;
        else {  // lowest-index tie-break; idx from LDS (rare path)
            int idxr[NSLOT];
            #pragma unroll
            for (int j = 0; j < NSLOT; ++j) {
                int p = lane + j * 64;
                idxr[j] = (p < cnt) ? (int)idxs[p] : 0x7FFF;
            }
            int l = -1, h = 8191;
            #pragma unroll 1
            while (h - l > 1) {
                int m = (l + h) >> 1;
                int c = 0;
                #pragma unroll
                for (int j = 0; j < NSLOT; ++j)
                    c += (int)__popcll(__ballot(key[j] == tauhi && idxr[j] <= m));
                if (c >= nT) h = m; else l = m;
            }
            cut = h;
        }
    }

    uint32_t selm = 0u;
    if (cut == -1) {
        #pragma unroll
        for (int j = 0; j < NSLOT; ++j) selm |= (key[j] > tauhi ? 1u : 0u) << j;
    } else if (cut == 0x7FFFFFFF) {
        #pragma unroll
        for (int j = 0; j < NSLOT; ++j) selm |= (key[j] >= tauhi ? 1u : 0u) << j;
    } else {
        #pragma unroll
        for (int j = 0; j < NSLOT; ++j) {
            int p = lane + j * 64;
            bool sj = (key[j] > tauhi) ||
                      (key[j] == tauhi && p < cnt && (int)idxs[p] <= cut);
            selm |= (sj ? 1u : 0u) << j;
        }
    }

    // LATE student gather: only the selected ~KSEL slots (batched; one drain)
    float svc[NSLOT];
    #pragma unroll
    for (int j = 0; j < NSLOT; ++j)
        svc[j] = (selm & (1u << j)) ? s[(int)idxs[lane + j * 64]] : 0.f;

    float St = 0.f, Stt = 0.f, Sts = 0.f, sm = -FLT_MAX;
    #pragma unroll
    for (int j = 0; j < NSLOT; ++j) {
        if (selm & (1u << j)) {
            float tv = keyf(key[j]);
            float e = __expf(tv - tmax);
            St += e; Stt += e * tv; Sts += e * svc[j];
            sm = fmaxf(sm, svc[j]);
        }
    }
    #pragma unroll
    for (int o = 32; o > 0; o >>= 1) {
        St  += __shfl_xor(St,  o, 64);
        Stt += __shfl_xor(Stt, o, 64);
        Sts += __shfl_xor(Sts, o, 64);
        sm = fmaxf(sm, __shfl_xor(sm, o, 64));
    }
    float Ss = 0.f;
    #pragma unroll
    for (int j = 0; j < NSLOT; ++j)
        if (selm & (1u << j)) Ss += __expf(svc[j] - sm);
    Ss = wave_sumf(Ss);
    if (lane == 0)
        return (Stt - Sts) / St - tmax - __logf(St) + sm + __logf(Ss);
    return 0.f;
}

// Exact top-KSEL + KL on dense register-resident keys, BALLOT bisection.
template <int NS, class IdxF>
__device__ float select_accum(uint32_t (&key)[NS], IdxF idxOf, const float* svp) {
    const int lane = threadIdx.x & 63;
    uint32_t kmx = 0u, kmn = 0xFFFFFFFFu;
    #pragma unroll
    for (int j = 0; j < NS; ++j) {
        uint32_t k = key[j];
        kmx = k > kmx ? k : kmx;
        kmn = k < kmn ? k : kmn;
    }
    #pragma unroll
    for (int o = 32; o > 0; o >>= 1) {
        uint32_t a = __shfl_xor(kmx, o, 64); kmx = a > kmx ? a : kmx;
        uint32_t b = __shfl_xor(kmn, o, 64); kmn = b < kmn ? b : kmn;
    }
    const float tmax = keyf(kmx);

    uint32_t lo = kmn - 1u, hi = kmx, tauhi = kmx;
    int cl = NS * 64, ch = 0, cut = -1;
    bool exact = false;
    #pragma unroll 1
    for (int it = 0; it < 80; ++it) {
        uint32_t span = hi - lo;
        if (span <= 1u) break;
        uint32_t mid;
        if (!(it & 1)) {
            uint64_t st = (uint64_t)span * (uint32_t)(cl - KSEL) / (uint32_t)(cl - ch);
            if (st < 1) st = 1;
            if (st > span - 1) st = span - 1;
            mid = lo + (uint32_t)st;
        } else mid = lo + (span >> 1);
        int c = 0;
        #pragma unroll
        for (int j = 0; j < NS; ++j)
            c += (int)__popcll(__ballot(key[j] > mid));
        if (c == KSEL) { tauhi = mid; exact = true; break; }
        if (c > KSEL) { lo = mid; cl = c; } else { hi = mid; ch = c; }
    }
    if (!exact) {
        tauhi = hi;
        const int nT = KSEL - ch, nTie = cl - ch;
        if (nT >= nTie) cut = 0x7FFFFFFF;
        else {
            int l = -1, h = NS * 64 - 1;
            #pragma unroll 1
            while (h - l > 1) {
                int m = (l + h) >> 1;
                int c = 0;
                #pragma unroll
                for (int j = 0; j < NS; ++j)
                    c += (int)__popcll(__ballot(key[j] == tauhi && idxOf(j) <= m));
                if (c >= nT) h = m; else l = m;
            }
            cut = h;
        }
    }

    float St = 0.f, Stt = 0.f, Sts = 0.f, sm = -FLT_MAX;
    #pragma unroll
    for (int j = 0; j < NS; ++j) {
        uint32_t kj = key[j];
        bool sj = (kj > tauhi) || (kj == tauhi && idxOf(j) <= cut);
        if (sj) {
            float tv = keyf(kj);
            float e = __expf(tv - tmax);
            St += e; Stt += e * tv; Sts += e * svp[j];
            sm = fmaxf(sm, svp[j]);
        }
    }
    #pragma unroll
    for (int o = 32; o > 0; o >>= 1) {
        St  += __shfl_xor(St,  o, 64);
        Stt += __shfl_xor(Stt, o, 64);
        Sts += __shfl_xor(Sts, o, 64);
        sm = fmaxf(sm, __shfl_xor(sm, o, 64));
    }
    float Ss = 0.f;
    #pragma unroll
    for (int j = 0; j < NS; ++j) {
        uint32_t kj = key[j];
        bool sj = (kj > tauhi) || (kj == tauhi && idxOf(j) <= cut);
        if (sj) Ss += __expf(svp[j] - sm);
    }
    Ss = wave_sumf(Ss);
    if (lane == 0)
        return (Stt - Sts) / St - tmax - __logf(St) + sm + __logf(Ss);
    return 0.f;
}

// mid groups (C = NJ*64): whole group + student prefetched to registers
template <int NJ>
__device__ float mid_wave(const float* __restrict__ t, const float* __restrict__ s) {
    const int lane = threadIdx.x & 63;
    const float4* t4 = (const float4*)t;
    const float4* s4 = (const float4*)s;
    uint32_t key[NJ];
    float svp[NJ];
    #pragma unroll
    for (int c = 0; c < NJ / 4; ++c) {
        float4 x = t4[lane + c * 64];
        float4 y = s4[lane + c * 64];
        key[4 * c + 0] = fkey(x.x); key[4 * c + 1] = fkey(x.y);
        key[4 * c + 2] = fkey(x.z); key[4 * c + 3] = fkey(x.w);
        svp[4 * c + 0] = y.x; svp[4 * c + 1] = y.y;
        svp[4 * c + 2] = y.z; svp[4 * c + 3] = y.w;
    }
    auto idxOf = [&](int j) { return ((lane + (j >> 2) * 64) << 2) + (j & 3); };
    return select_accum<NJ>(key, idxOf, svp);
}

// tiny groups (k == C <= 256): whole-group softmax; returns kl on lane 0
__device__ float tiny_group(const float* __restrict__ t, const float* __restrict__ s,
                            int Cg) {
    const int lane = threadIdx.x & 63;
    float St = 0.f, Stt = 0.f, Sts = 0.f, m = -FLT_MAX, l = 0.f;
    float tv[4], svv[4];
    #pragma unroll
    for (int q = 0; q < 4; ++q) {
        int i = lane + q * 64;
        bool va = i < Cg;
        tv[q] = va ? t[i] : -FLT_MAX;
        svv[q] = va ? s[i] : 0.f;
    }
    float mx = -FLT_MAX;
    #pragma unroll
    for (int q = 0; q < 4; ++q) mx = fmaxf(mx, tv[q]);
    mx = wave_maxf(mx);
    #pragma unroll
    for (int q = 0; q < 4; ++q) {
        if (lane + q * 64 < Cg) {
            float e = __expf(tv[q] - mx);
            St += e; Stt += e * tv[q]; Sts += e * svv[q];
            float x = svv[q];
            if (x > m) { l = l * __expf(m - x) + 1.f; m = x; }
            else       { l += __expf(x - m); }
        }
    }
    #pragma unroll
    for (int o = 32; o > 0; o >>= 1) {
        St  += __shfl_xor(St,  o, 64);
        Stt += __shfl_xor(Stt, o, 64);
        Sts += __shfl_xor(Sts, o, 64);
        float m2 = __shfl_xor(m, o, 64);
        float l2 = __shfl_xor(l, o, 64);
        lse_merge(m, l, m2, l2);
    }
    if (lane == 0)
        return (Stt - Sts) / St - mx - __logf(St) + m + __logf(l);
    return 0.f;
}

// ONE WAVE = ONE BLOCK = ONE job; five job types (champion R10 structure):
//   job 0: g0 (8192)  job 1: g1 (4096)  job 2: g2 (2048)
//   job 3: g3 (1024)  job 4: g4 (512) + tinies
// No barriers; heavy jobs dispatch first. LDS 7.7 KB; VGPR 48 (no spills).
// Residency is HW-capped at ~16 workgroups/CU (R13/R15 ruled out occupancy
// pushes: tighter launch_bounds spill; LDS shrink doesn't lift the cap).
__global__ __launch_bounds__(64, 4) void kd_jobs(const float* __restrict__ sL,
                                                 const float* __restrict__ tL,
                                                 float* __restrict__ partial) {
    __shared__ float    vals[CAP];    // 5 KiB
    __shared__ uint16_t idxs[CAP];    // 2.5 KiB
    const int bid = blockIdx.x;
    const int job = bid >> 10;
    const int row = bid & 1023;
    const float* tr = tL + (size_t)row * TOTAL;
    const float* sr = sL + (size_t)row * TOTAL;

    float kl = 0.f;
    switch (job) {
    case 0:
        kl = big_wave<32>(tr, sr, 1.10f, vals, idxs);
        break;
    case 1:
        kl = big_wave<16>(tr + 8192, sr + 8192, 0.60f, vals, idxs);
        break;
    case 2:
        kl = big_wave<8>(tr + 12288, sr + 12288, 0.50f, vals, idxs);
        break;
    case 3:
        kl = mid_wave<16>(tr + 14336, sr + 14336);
        break;
    default:
        kl  = mid_wave<8>(tr + 15360, sr + 15360);
        kl += tiny_group(tr + 15872, sr + 15872, 256);
        kl += tiny_group(tr + 16128, sr + 16128, 128);
        kl += tiny_group(tr + 16256, sr + 16256, 64);
        kl += tiny_group(tr + 16320, sr + 16320, 32);
        kl += tiny_group(tr + 16352, sr + 16352, 16);
        break;
    }

    if ((threadIdx.x & 63) == 0)
        atomicAdd(&partial[(row + job * 37) & (NBUCKET - 1)], kl * (0.1f / 1024.f));
}

__global__ void zero_ws(float* partial) {
    if (threadIdx.x < NBUCKET) partial[threadIdx.x] = 0.f;
}

__global__ void final_sum(const float* __restrict__ partial, float* __restrict__ out) {
    float v = (threadIdx.x < NBUCKET) ? partial[threadIdx.x] : 0.f;
    #pragma unroll
    for (int o = 32; o > 0; o >>= 1) v += __shfl_down(v, o, 64);
    if (threadIdx.x == 0) out[0] = v;
}

extern "C" void kernel_launch(void* const* d_in, const int* in_sizes, int n_in,
                              void* d_out, int out_size, void* d_ws, size_t ws_size,
                              hipStream_t stream) {
    (void)in_sizes; (void)n_in; (void)ws_size; (void)out_size;
    const float* s = (const float*)d_in[0];
    const float* t = (const float*)d_in[1];
    float* out = (float*)d_out;
    float* ws = (float*)d_ws;

    hipLaunchKernelGGL(zero_ws, dim3(1), dim3(64), 0, stream, ws);
    hipLaunchKernelGGL(kd_jobs, dim3(5120), dim3(64), 0, stream, s, t, ws);
    hipLaunchKernelGGL(final_sum, dim3(1), dim3(64), 0, stream, ws, out);
}